// Round 4
// baseline (411.303 us; speedup 1.0000x reference)
//
#include <hip/hip_runtime.h>

// Problem: B=8, LQ=LK=2048, D=64.
// out0 = output [8,2048,64] f32 ; out1 = attn [8,2048,2048] f32 (concat flat).
// R3 lesson: occupancy lever exhausted (512-thr blocks didn't co-schedule;
// VGPR=56 shows compiler keeps only ~5 loads in flight -> 2.4 TB/s).
// R4: same 1024x256 geometry (keeps 414MB fetch / 131MB write traffic),
// explicit 5-phase pipeline in the kb loop to force ~12 feature loads in
// flight per wave, nontemporal attn stores to preserve L3 for the f-stream.

#define BBn 8
#define LQn 2048
#define LKn 2048
#define DDn 64

typedef _Float16 half8 __attribute__((ext_vector_type(8)));
typedef _Float16 half4 __attribute__((ext_vector_type(4)));
typedef float floatx4 __attribute__((ext_vector_type(4)));
typedef int intx4 __attribute__((ext_vector_type(4)));

// ---------------- mask dtype detection ----------------
// mode 0: int32 {0,1}; mode 1: float32 {0.0,1.0}; mode 2: byte bools.
__global__ __launch_bounds__(256) void detect_mask(const unsigned* __restrict__ m,
                                                   int* __restrict__ flag) {
  __shared__ int s_int, s_f32;
  const int tid = threadIdx.x;
  if (tid == 0) { s_int = 1; s_f32 = 1; }
  __syncthreads();
  int oki = 1, okf = 1;
  for (int i = tid; i < 4096; i += 256) {
    unsigned x = m[i];
    oki &= (x <= 1u);
    okf &= (x == 0u || x == 0x3f800000u);
  }
  atomicAnd(&s_int, oki);
  atomicAnd(&s_f32, okf);
  __syncthreads();
  if (tid == 0) *flag = s_int ? 0 : (s_f32 ? 1 : 2);
}

// ---------------- kernel A: logits + unnormalized exp + row sums ----------
// grid = 1024 (b*128 + qtile); 256 threads = 4 waves, wave w owns keys
// [w*512, w*512+512), 8 kb-iterations of 64 keys.
__global__ __launch_bounds__(256, 4) void attn_logits(
    const float* __restrict__ qp, const float* __restrict__ kp,
    const float* __restrict__ f1, const float* __restrict__ f2,
    const float* __restrict__ f3, const float* __restrict__ f4,
    const float* __restrict__ f5,
    const void* __restrict__ maskp, const int* __restrict__ flag,
    float* __restrict__ attn, float* __restrict__ invl) {
  const int blk = blockIdx.x;           // 1024 blocks: 8 b * 128 q-tiles
  const int b   = blk >> 7;
  const int q0  = (blk & 127) << 4;     // 16 q rows per block
  const int tid = threadIdx.x;
  const int w   = tid >> 6;             // wave 0..3 (splits the 2048 keys)
  const int l   = tid & 63;
  const int lr  = l & 15;
  const int lgp = l >> 4;
  const int mode = *flag;

  // Q A-fragments: A[row=lr][d = dc*32 + lgp*8 + i]
  const float* qrow = qp + ((size_t)(b * LQn + q0 + lr)) * DDn;
  half8 aq[2];
#pragma unroll
  for (int dc = 0; dc < 2; ++dc) {
    floatx4 x0 = *(const floatx4*)(qrow + dc * 32 + lgp * 8);
    floatx4 x1 = *(const floatx4*)(qrow + dc * 32 + lgp * 8 + 4);
    half8 h;
#pragma unroll
    for (int i = 0; i < 4; ++i) { h[i] = (_Float16)x0[i]; h[i + 4] = (_Float16)x1[i]; }
    aq[dc] = h;
  }

  float lsum[4] = {0.f, 0.f, 0.f, 0.f};
  const size_t rowbase = (size_t)b * LQn + q0;
  const int t0 = w * 512;

  for (int kb = t0; kb < t0 + 512; kb += 64) {
    const size_t col = (size_t)(kb + 4 * lr);
    size_t fof[4];
#pragma unroll
    for (int r = 0; r < 4; ++r) fof[r] = (rowbase + lgp * 4 + r) * (size_t)LKn + col;

    // ---- Phase A: issue feature+mask loads for rows 0,1 (no uses) ----
    floatx4 a1_0, a2_0, a3_0, a4_0, a5_0, a1_1, a2_1, a3_1, a4_1, a5_1;
    intx4 mi_0, mi_1; floatx4 mf_0, mf_1; unsigned mb_0 = 0, mb_1 = 0;
    a1_0 = *(const floatx4*)(f1 + fof[0]); a1_1 = *(const floatx4*)(f1 + fof[1]);
    a2_0 = *(const floatx4*)(f2 + fof[0]); a2_1 = *(const floatx4*)(f2 + fof[1]);
    a3_0 = *(const floatx4*)(f3 + fof[0]); a3_1 = *(const floatx4*)(f3 + fof[1]);
    a4_0 = *(const floatx4*)(f4 + fof[0]); a4_1 = *(const floatx4*)(f4 + fof[1]);
    a5_0 = *(const floatx4*)(f5 + fof[0]); a5_1 = *(const floatx4*)(f5 + fof[1]);
    if (mode == 0) {
      mi_0 = *(const intx4*)((const int*)maskp + fof[0]);
      mi_1 = *(const intx4*)((const int*)maskp + fof[1]);
    } else if (mode == 1) {
      mf_0 = *(const floatx4*)((const float*)maskp + fof[0]);
      mf_1 = *(const floatx4*)((const float*)maskp + fof[1]);
    } else {
      mb_0 = *(const unsigned*)((const unsigned char*)maskp + fof[0]);
      mb_1 = *(const unsigned*)((const unsigned char*)maskp + fof[1]);
    }

    // ---- Phase B: K loads + MFMA (covers phase-A latency) ----
    floatx4 acc[4];
#pragma unroll
    for (int jj = 0; jj < 4; ++jj) acc[jj] = (floatx4){0.f, 0.f, 0.f, 0.f};
#pragma unroll
    for (int dc = 0; dc < 2; ++dc) {
#pragma unroll
      for (int jj = 0; jj < 4; ++jj) {
        const float* krow =
            kp + ((size_t)(b * LKn + kb + 4 * lr + jj)) * DDn + dc * 32 + lgp * 8;
        floatx4 x0 = *(const floatx4*)(krow);
        floatx4 x1 = *(const floatx4*)(krow + 4);
        half8 h;
#pragma unroll
        for (int i = 0; i < 4; ++i) { h[i] = (_Float16)x0[i]; h[i + 4] = (_Float16)x1[i]; }
        acc[jj] = __builtin_amdgcn_mfma_f32_16x16x32_f16(aq[dc], h, acc[jj], 0, 0, 0);
      }
    }

    // ---- Phase C: issue feature+mask loads for rows 2,3 ----
    floatx4 c1_2, c2_2, c3_2, c4_2, c5_2, c1_3, c2_3, c3_3, c4_3, c5_3;
    intx4 mi_2, mi_3; floatx4 mf_2, mf_3; unsigned mb_2 = 0, mb_3 = 0;
    c1_2 = *(const floatx4*)(f1 + fof[2]); c1_3 = *(const floatx4*)(f1 + fof[3]);
    c2_2 = *(const floatx4*)(f2 + fof[2]); c2_3 = *(const floatx4*)(f2 + fof[3]);
    c3_2 = *(const floatx4*)(f3 + fof[2]); c3_3 = *(const floatx4*)(f3 + fof[3]);
    c4_2 = *(const floatx4*)(f4 + fof[2]); c4_3 = *(const floatx4*)(f4 + fof[3]);
    c5_2 = *(const floatx4*)(f5 + fof[2]); c5_3 = *(const floatx4*)(f5 + fof[3]);
    if (mode == 0) {
      mi_2 = *(const intx4*)((const int*)maskp + fof[2]);
      mi_3 = *(const intx4*)((const int*)maskp + fof[3]);
    } else if (mode == 1) {
      mf_2 = *(const floatx4*)((const float*)maskp + fof[2]);
      mf_3 = *(const floatx4*)((const float*)maskp + fof[3]);
    } else {
      mb_2 = *(const unsigned*)((const unsigned char*)maskp + fof[2]);
      mb_3 = *(const unsigned*)((const unsigned char*)maskp + fof[3]);
    }

    // ---- Phase D: consume rows 0,1 (r23 loads still in flight) ----
#pragma unroll
    for (int r = 0; r < 2; ++r) {
      floatx4 v1 = r ? a1_1 : a1_0, v2 = r ? a2_1 : a2_0, v3 = r ? a3_1 : a3_0;
      floatx4 v4 = r ? a4_1 : a4_0, v5 = r ? a5_1 : a5_0;
      int msk[4];
      if (mode == 0) {
        intx4 m4 = r ? mi_1 : mi_0;
        msk[0] = (m4[0] != 0); msk[1] = (m4[1] != 0);
        msk[2] = (m4[2] != 0); msk[3] = (m4[3] != 0);
      } else if (mode == 1) {
        floatx4 m4 = r ? mf_1 : mf_0;
        msk[0] = (m4[0] != 0.f); msk[1] = (m4[1] != 0.f);
        msk[2] = (m4[2] != 0.f); msk[3] = (m4[3] != 0.f);
      } else {
        unsigned mv = r ? mb_1 : mb_0;
        msk[0] = (int)(mv & 0xffu); msk[1] = (int)((mv >> 8) & 0xffu);
        msk[2] = (int)((mv >> 16) & 0xffu); msk[3] = (int)((mv >> 24) & 0xffu);
      }
      floatx4 ev;
#pragma unroll
      for (int jj = 0; jj < 4; ++jj) {
        float lgt = (acc[jj][r] + v1[jj] + v2[jj] + v3[jj] + v4[jj] + v5[jj]) * 0.125f;
        float e = msk[jj] ? 0.f : __expf(lgt - 16.f);  // logits < 8 -> no overflow
        ev[jj] = e;
        lsum[r] += e;
      }
      __builtin_nontemporal_store(ev, (floatx4*)(attn + fof[r]));
    }

    // ---- Phase E: consume rows 2,3 ----
#pragma unroll
    for (int r = 2; r < 4; ++r) {
      floatx4 v1 = (r == 3) ? c1_3 : c1_2, v2 = (r == 3) ? c2_3 : c2_2;
      floatx4 v3 = (r == 3) ? c3_3 : c3_2, v4 = (r == 3) ? c4_3 : c4_2;
      floatx4 v5 = (r == 3) ? c5_3 : c5_2;
      int msk[4];
      if (mode == 0) {
        intx4 m4 = (r == 3) ? mi_3 : mi_2;
        msk[0] = (m4[0] != 0); msk[1] = (m4[1] != 0);
        msk[2] = (m4[2] != 0); msk[3] = (m4[3] != 0);
      } else if (mode == 1) {
        floatx4 m4 = (r == 3) ? mf_3 : mf_2;
        msk[0] = (m4[0] != 0.f); msk[1] = (m4[1] != 0.f);
        msk[2] = (m4[2] != 0.f); msk[3] = (m4[3] != 0.f);
      } else {
        unsigned mv = (r == 3) ? mb_3 : mb_2;
        msk[0] = (int)(mv & 0xffu); msk[1] = (int)((mv >> 8) & 0xffu);
        msk[2] = (int)((mv >> 16) & 0xffu); msk[3] = (int)((mv >> 24) & 0xffu);
      }
      floatx4 ev;
#pragma unroll
      for (int jj = 0; jj < 4; ++jj) {
        float lgt = (acc[jj][r] + v1[jj] + v2[jj] + v3[jj] + v4[jj] + v5[jj]) * 0.125f;
        float e = msk[jj] ? 0.f : __expf(lgt - 16.f);
        ev[jj] = e;
        lsum[r] += e;
      }
      __builtin_nontemporal_store(ev, (floatx4*)(attn + fof[r]));
    }
  }

  // reduce lsum over the 16 lanes of each group (cols), then across 4 waves
#pragma unroll
  for (int off = 1; off < 16; off <<= 1) {
#pragma unroll
    for (int r = 0; r < 4; ++r) lsum[r] += __shfl_xor(lsum[r], off);
  }
  __shared__ float lds_l[4][16];
  if (lr == 0) {
#pragma unroll
    for (int r = 0; r < 4; ++r) lds_l[w][lgp * 4 + r] = lsum[r];
  }
  __syncthreads();
  if (tid < 16) {
    float s = lds_l[0][tid] + lds_l[1][tid] + lds_l[2][tid] + lds_l[3][tid];
    invl[rowbase + tid] = 1.0f / s;
  }
}

// ---------------- kernel B: normalize attn + PV ----------------
__global__ __launch_bounds__(256, 4) void attn_pv(
    const float* __restrict__ vp, const float* __restrict__ invl,
    float* __restrict__ attn, float* __restrict__ outp) {
  const int blk = blockIdx.x;
  const int b   = blk >> 7;
  const int q0  = (blk & 127) << 4;
  const int tid = threadIdx.x;
  const int w   = tid >> 6;
  const int l   = tid & 63;
  const int lr  = l & 15;
  const int lgp = l >> 4;

  __shared__ __align__(16) _Float16 p16[4][16][72];  // +8 pad per row: bank spread
  __shared__ float osum[4][16][64];

  const size_t rowbase = (size_t)b * LQn + q0;
  float il[4];
#pragma unroll
  for (int r = 0; r < 4; ++r) il[r] = invl[rowbase + lgp * 4 + r];

  floatx4 acc[4];
#pragma unroll
  for (int dt = 0; dt < 4; ++dt) acc[dt] = (floatx4){0.f, 0.f, 0.f, 0.f};

  const int t0 = w * 512;
  for (int kb = t0; kb < t0 + 512; kb += 64) {
    // read e (same lane/address we then overwrite -> program order safe),
    // normalize, write p, stash f16 copy in per-wave LDS tile
#pragma unroll
    for (int r = 0; r < 4; ++r) {
      const int row = lgp * 4 + r;
      const size_t fof = (rowbase + row) * (size_t)LKn + (size_t)(kb + 4 * lr);
      floatx4 e = __builtin_nontemporal_load((const floatx4*)(attn + fof));
      floatx4 p = e * il[r];
      __builtin_nontemporal_store(p, (floatx4*)(attn + fof));
      half4 hp;
#pragma unroll
      for (int jj = 0; jj < 4; ++jj) hp[jj] = (_Float16)p[jj];
      *(half4*)(&p16[w][row][4 * lr]) = hp;
    }
    // A-frags for PV from LDS (per-wave buffer; same-wave LDS ops are in order)
    half8 pa[2];
#pragma unroll
    for (int tc = 0; tc < 2; ++tc)
      pa[tc] = *(const half8*)(&p16[w][lr][tc * 32 + lgp * 8]);
    // V B-frags (column reads via L2; V[b] is L2-resident) + MFMA
#pragma unroll
    for (int tc = 0; tc < 2; ++tc) {
#pragma unroll
      for (int dt = 0; dt < 4; ++dt) {
        const float* vbase =
            vp + ((size_t)(b * LKn + kb + tc * 32 + lgp * 8)) * DDn + dt * 16 + lr;
        half8 bv;
#pragma unroll
        for (int i = 0; i < 8; ++i) bv[i] = (_Float16)vbase[i * DDn];
        acc[dt] = __builtin_amdgcn_mfma_f32_16x16x32_f16(pa[tc], bv, acc[dt], 0, 0, 0);
      }
    }
  }

  // cross-wave reduction of out partials
#pragma unroll
  for (int dt = 0; dt < 4; ++dt) {
#pragma unroll
    for (int r = 0; r < 4; ++r) osum[w][lgp * 4 + r][dt * 16 + lr] = acc[dt][r];
  }
  __syncthreads();
#pragma unroll
  for (int ii = 0; ii < 4; ++ii) {
    int idx = tid + 256 * ii;
    int row = idx >> 6, d = idx & 63;
    float s = osum[0][row][d] + osum[1][row][d] + osum[2][row][d] + osum[3][row][d];
    outp[(rowbase + row) * DDn + d] = s;
  }
}

extern "C" void kernel_launch(void* const* d_in, const int* in_sizes, int n_in,
                              void* d_out, int out_size, void* d_ws, size_t ws_size,
                              hipStream_t stream) {
  const float* q  = (const float*)d_in[0];
  const float* k  = (const float*)d_in[1];
  const float* v  = (const float*)d_in[2];
  const void*  mask = d_in[3];
  const float* f1 = (const float*)d_in[4];
  const float* f2 = (const float*)d_in[5];
  const float* f3 = (const float*)d_in[6];
  const float* f4 = (const float*)d_in[7];
  const float* f5 = (const float*)d_in[8];

  float* outp = (float*)d_out;
  float* attn = outp + (size_t)BBn * LQn * DDn;  // 1,048,576 floats in
  float* invl = (float*)d_ws;                    // 16384 floats
  int*   flag = (int*)d_ws + (BBn * LQn);        // 1 int after invl

  detect_mask<<<1, 256, 0, stream>>>((const unsigned*)mask, flag);
  attn_logits<<<1024, 256, 0, stream>>>(q, k, f1, f2, f3, f4, f5, mask, flag, attn, invl);
  attn_pv<<<1024, 256, 0, stream>>>(v, invl, attn, outp);
}

// Round 5
// 294.453 us; speedup vs baseline: 1.3968x; 1.3968x over previous
//
#include <hip/hip_runtime.h>

// Problem: B=8, LQ=LK=2048, D=64.
// out0 = output [8,2048,64] f32 ; out1 = attn [8,2048,2048] f32 (concat flat).
// R4 lesson: nontemporal stores = 3.6x write amplification (131->477MB) +
// RMW fetch amplification. Reverted.
// R5: cut cache-side delivered bytes + VMEM instr count:
//   - prep kernel: K -> f16 linear (2MB), V -> f16 MFMA-B-frag layout (2MB).
//   - kernel A: 32-row q-tiles (512 blocks x 512 thr): one K B-frag feeds
//     2 A-tiles (K bytes/output halved twice vs R3), no in-loop cvts.
//   - kernel B: V loads become 8x half8 instead of 64 scalar dwords/iter.
// Fallback to R3-style f32 kernels if ws_size < 4.3MB.

#define BBn 8
#define LQn 2048
#define LKn 2048
#define DDn 64

typedef _Float16 half8 __attribute__((ext_vector_type(8)));
typedef _Float16 half4 __attribute__((ext_vector_type(4)));
typedef float floatx4 __attribute__((ext_vector_type(4)));
typedef int intx4 __attribute__((ext_vector_type(4)));

// ---------------- prep: mask detect + K/V f16 fragmentation ----------------
// grid 1025 x 256. blk<512: K->f16 linear. blk in [512,1024): V->frag layout.
// blk==1024: mask dtype detect (mode 0 int32, 1 f32, 2 byte).
__global__ __launch_bounds__(256) void prep_all(
    const float* __restrict__ kp, const float* __restrict__ vp,
    const unsigned* __restrict__ m, _Float16* __restrict__ kh,
    _Float16* __restrict__ vh, int* __restrict__ flag) {
  const int blk = blockIdx.x;
  const int tid = threadIdx.x;
  if (blk < 512) {
    const size_t off = ((size_t)blk * 256 + tid) * 8;
    floatx4 x0 = *(const floatx4*)(kp + off);
    floatx4 x1 = *(const floatx4*)(kp + off + 4);
    half8 h;
#pragma unroll
    for (int i = 0; i < 4; ++i) { h[i] = (_Float16)x0[i]; h[i + 4] = (_Float16)x1[i]; }
    *(half8*)(kh + off) = h;
  } else if (blk < 1024) {
    int fid = (blk - 512) * 256 + tid;      // 17-bit id
    const int lr  = fid & 15;  fid >>= 4;
    const int lgp = fid & 3;   fid >>= 2;
    const int dt  = fid & 3;   fid >>= 2;
    const int tc  = fid & 1;   fid >>= 1;
    const int kb6 = fid & 31;  fid >>= 5;
    const int b   = fid;       // 0..7
    const float* vbase =
        vp + ((size_t)(b * LKn + kb6 * 64 + tc * 32 + lgp * 8)) * DDn + dt * 16 + lr;
    half8 h;
#pragma unroll
    for (int i = 0; i < 8; ++i) h[i] = (_Float16)vbase[i * DDn];
    const size_t vof =
        ((((((size_t)b * 32 + kb6) * 2 + tc) * 4 + dt) * 4 + lgp) * 16 + lr) * 8;
    *(half8*)(vh + vof) = h;
  } else {
    __shared__ int s_int, s_f32;
    if (tid == 0) { s_int = 1; s_f32 = 1; }
    __syncthreads();
    int oki = 1, okf = 1;
    for (int i = tid; i < 4096; i += 256) {
      unsigned x = m[i];
      oki &= (x <= 1u);
      okf &= (x == 0u || x == 0x3f800000u);
    }
    atomicAnd(&s_int, oki);
    atomicAnd(&s_f32, okf);
    __syncthreads();
    if (tid == 0) *flag = s_int ? 0 : (s_f32 ? 1 : 2);
  }
}

__global__ __launch_bounds__(256) void detect_mask(const unsigned* __restrict__ m,
                                                   int* __restrict__ flag) {
  __shared__ int s_int, s_f32;
  const int tid = threadIdx.x;
  if (tid == 0) { s_int = 1; s_f32 = 1; }
  __syncthreads();
  int oki = 1, okf = 1;
  for (int i = tid; i < 4096; i += 256) {
    unsigned x = m[i];
    oki &= (x <= 1u);
    okf &= (x == 0u || x == 0x3f800000u);
  }
  atomicAnd(&s_int, oki);
  atomicAnd(&s_f32, okf);
  __syncthreads();
  if (tid == 0) *flag = s_int ? 0 : (s_f32 ? 1 : 2);
}

// ---------------- kernel A: 32-row tiles, f16 K frags ----------------------
// grid 512 (b*64 + qt, 32 rows); 512 thr = 8 waves, wave w owns keys
// [w*256, w*256+256) -> 4 iters of 64 keys x 32 rows (2 MFMA A-tiles).
__global__ __launch_bounds__(512, 4) void attn_logits32(
    const float* __restrict__ qp, const _Float16* __restrict__ kh,
    const float* __restrict__ f1, const float* __restrict__ f2,
    const float* __restrict__ f3, const float* __restrict__ f4,
    const float* __restrict__ f5,
    const void* __restrict__ maskp, const int* __restrict__ flag,
    float* __restrict__ attn, float* __restrict__ invl) {
  const int blk = blockIdx.x;           // 512 blocks: 8 b * 64 q-tiles
  const int b   = blk >> 6;
  const int q0  = (blk & 63) << 5;      // 32 q rows per block
  const int tid = threadIdx.x;
  const int w   = tid >> 6;             // wave 0..7
  const int l   = tid & 63;
  const int lr  = l & 15;
  const int lgp = l >> 4;
  const int mode = *flag;

  // Q A-fragments for 2 tiles: A[t][row=lr][d = dc*32 + lgp*8 + i]
  half8 aq[2][2];
#pragma unroll
  for (int t = 0; t < 2; ++t) {
    const float* qrow = qp + ((size_t)(b * LQn + q0 + t * 16 + lr)) * DDn;
#pragma unroll
    for (int dc = 0; dc < 2; ++dc) {
      floatx4 x0 = *(const floatx4*)(qrow + dc * 32 + lgp * 8);
      floatx4 x1 = *(const floatx4*)(qrow + dc * 32 + lgp * 8 + 4);
      half8 h;
#pragma unroll
      for (int i = 0; i < 4; ++i) { h[i] = (_Float16)x0[i]; h[i + 4] = (_Float16)x1[i]; }
      aq[t][dc] = h;
    }
  }

  float lsum[2][4] = {{0.f, 0.f, 0.f, 0.f}, {0.f, 0.f, 0.f, 0.f}};
  const size_t rowbase = (size_t)b * LQn + q0;
  const int t0 = w * 256;

  for (int kb = t0; kb < t0 + 256; kb += 64) {
    // S-tiles: 32 q x 64 keys. Column j -> key kb + 4*j + jj (contiguous x4).
    floatx4 acc[2][4];
#pragma unroll
    for (int t = 0; t < 2; ++t)
#pragma unroll
      for (int jj = 0; jj < 4; ++jj) acc[t][jj] = (floatx4){0.f, 0.f, 0.f, 0.f};
#pragma unroll
    for (int dc = 0; dc < 2; ++dc) {
#pragma unroll
      for (int jj = 0; jj < 4; ++jj) {
        half8 bk = *(const half8*)(
            kh + ((size_t)(b * LKn + kb + 4 * lr + jj)) * DDn + dc * 32 + lgp * 8);
#pragma unroll
        for (int t = 0; t < 2; ++t)
          acc[t][jj] = __builtin_amdgcn_mfma_f32_16x16x32_f16(aq[t][dc], bk, acc[t][jj], 0, 0, 0);
      }
    }
    // consume: 8 rows per lane (2 tiles x 4 r)
#pragma unroll
    for (int t = 0; t < 2; ++t) {
#pragma unroll
      for (int r = 0; r < 4; ++r) {
        const int row = t * 16 + lgp * 4 + r;
        const size_t fof = (rowbase + row) * (size_t)LKn + (size_t)(kb + 4 * lr);
        floatx4 v1 = *(const floatx4*)(f1 + fof);
        floatx4 v2 = *(const floatx4*)(f2 + fof);
        floatx4 v3 = *(const floatx4*)(f3 + fof);
        floatx4 v4 = *(const floatx4*)(f4 + fof);
        floatx4 v5 = *(const floatx4*)(f5 + fof);
        int msk[4];
        if (mode == 0) {
          intx4 m4 = *(const intx4*)((const int*)maskp + fof);
          msk[0] = (m4[0] != 0); msk[1] = (m4[1] != 0);
          msk[2] = (m4[2] != 0); msk[3] = (m4[3] != 0);
        } else if (mode == 1) {
          floatx4 m4 = *(const floatx4*)((const float*)maskp + fof);
          msk[0] = (m4[0] != 0.f); msk[1] = (m4[1] != 0.f);
          msk[2] = (m4[2] != 0.f); msk[3] = (m4[3] != 0.f);
        } else {
          unsigned mv = *(const unsigned*)((const unsigned char*)maskp + fof);
          msk[0] = (int)(mv & 0xffu); msk[1] = (int)((mv >> 8) & 0xffu);
          msk[2] = (int)((mv >> 16) & 0xffu); msk[3] = (int)((mv >> 24) & 0xffu);
        }
        floatx4 ev;
#pragma unroll
        for (int jj = 0; jj < 4; ++jj) {
          float lgt = (acc[t][jj][r] + v1[jj] + v2[jj] + v3[jj] + v4[jj] + v5[jj]) * 0.125f;
          float e = msk[jj] ? 0.f : __expf(lgt - 16.f);  // logits < 8, no overflow
          ev[jj] = e;
          lsum[t][r] += e;
        }
        *(floatx4*)(attn + fof) = ev;
      }
    }
  }

  // reduce over the 16 lanes of each group, then across 8 waves
#pragma unroll
  for (int off = 1; off < 16; off <<= 1) {
#pragma unroll
    for (int t = 0; t < 2; ++t)
#pragma unroll
      for (int r = 0; r < 4; ++r) lsum[t][r] += __shfl_xor(lsum[t][r], off);
  }
  __shared__ float lds_l[8][32];
  if (lr == 0) {
#pragma unroll
    for (int t = 0; t < 2; ++t)
#pragma unroll
      for (int r = 0; r < 4; ++r) lds_l[w][t * 16 + lgp * 4 + r] = lsum[t][r];
  }
  __syncthreads();
  if (tid < 32) {
    float s = 0.f;
#pragma unroll
    for (int ww = 0; ww < 8; ++ww) s += lds_l[ww][tid];
    invl[rowbase + tid] = 1.0f / s;
  }
}

// ---------------- kernel B: normalize attn + PV (f16 V frags) --------------
__global__ __launch_bounds__(256, 4) void attn_pv(
    const _Float16* __restrict__ vh, const float* __restrict__ invl,
    float* __restrict__ attn, float* __restrict__ outp) {
  const int blk = blockIdx.x;
  const int b   = blk >> 7;
  const int q0  = (blk & 127) << 4;
  const int tid = threadIdx.x;
  const int w   = tid >> 6;
  const int l   = tid & 63;
  const int lr  = l & 15;
  const int lgp = l >> 4;

  __shared__ __align__(16) _Float16 p16[4][16][72];  // +8 pad per row
  __shared__ float osum[4][16][64];

  const size_t rowbase = (size_t)b * LQn + q0;
  float il[4];
#pragma unroll
  for (int r = 0; r < 4; ++r) il[r] = invl[rowbase + lgp * 4 + r];

  floatx4 acc[4];
#pragma unroll
  for (int dt = 0; dt < 4; ++dt) acc[dt] = (floatx4){0.f, 0.f, 0.f, 0.f};

  const int t0 = w * 512;
  for (int kb = t0; kb < t0 + 512; kb += 64) {
    const int kb6 = kb >> 6;
    // read e (same lane/address we then overwrite -> program order safe),
    // normalize, write p, stash f16 copy in per-wave LDS tile
#pragma unroll
    for (int r = 0; r < 4; ++r) {
      const int row = lgp * 4 + r;
      const size_t fof = (rowbase + row) * (size_t)LKn + (size_t)(kb + 4 * lr);
      floatx4 e = *(const floatx4*)(attn + fof);
      floatx4 p = e * il[r];
      *(floatx4*)(attn + fof) = p;
      half4 hp;
#pragma unroll
      for (int jj = 0; jj < 4; ++jj) hp[jj] = (_Float16)p[jj];
      *(half4*)(&p16[w][row][4 * lr]) = hp;
    }
    // A-frags for PV from LDS (per-wave buffer; same-wave LDS ops in order)
    half8 pa[2];
#pragma unroll
    for (int tc = 0; tc < 2; ++tc)
      pa[tc] = *(const half8*)(&p16[w][lr][tc * 32 + lgp * 8]);
    // V B-frags: one half8 load each (prepped layout)
#pragma unroll
    for (int tc = 0; tc < 2; ++tc) {
#pragma unroll
      for (int dt = 0; dt < 4; ++dt) {
        half8 bv = *(const half8*)(
            vh + ((((((size_t)b * 32 + kb6) * 2 + tc) * 4 + dt) * 4 + lgp) * 16 + lr) * 8);
        acc[dt] = __builtin_amdgcn_mfma_f32_16x16x32_f16(pa[tc], bv, acc[dt], 0, 0, 0);
      }
    }
  }

  // cross-wave reduction of out partials
#pragma unroll
  for (int dt = 0; dt < 4; ++dt) {
#pragma unroll
    for (int r = 0; r < 4; ++r) osum[w][lgp * 4 + r][dt * 16 + lr] = acc[dt][r];
  }
  __syncthreads();
#pragma unroll
  for (int ii = 0; ii < 4; ++ii) {
    int idx = tid + 256 * ii;
    int row = idx >> 6, d = idx & 63;
    float s = osum[0][row][d] + osum[1][row][d] + osum[2][row][d] + osum[3][row][d];
    outp[(rowbase + row) * DDn + d] = s;
  }
}

// ---------------- fallback (R3 geometry, f32 K/V) if ws too small ----------
__global__ __launch_bounds__(512, 4) void attn_logits_fb(
    const float* __restrict__ qp, const float* __restrict__ kp,
    const float* __restrict__ f1, const float* __restrict__ f2,
    const float* __restrict__ f3, const float* __restrict__ f4,
    const float* __restrict__ f5,
    const void* __restrict__ maskp, const int* __restrict__ flag,
    float* __restrict__ attn, float* __restrict__ invl) {
  const int blk = blockIdx.x;
  const int b   = blk >> 7;
  const int q0  = (blk & 127) << 4;
  const int tid = threadIdx.x;
  const int w   = tid >> 6;
  const int l   = tid & 63;
  const int lr  = l & 15;
  const int lgp = l >> 4;
  const int mode = *flag;
  const float* qrow = qp + ((size_t)(b * LQn + q0 + lr)) * DDn;
  half8 aq[2];
#pragma unroll
  for (int dc = 0; dc < 2; ++dc) {
    floatx4 x0 = *(const floatx4*)(qrow + dc * 32 + lgp * 8);
    floatx4 x1 = *(const floatx4*)(qrow + dc * 32 + lgp * 8 + 4);
    half8 h;
#pragma unroll
    for (int i = 0; i < 4; ++i) { h[i] = (_Float16)x0[i]; h[i + 4] = (_Float16)x1[i]; }
    aq[dc] = h;
  }
  float lsum[4] = {0.f, 0.f, 0.f, 0.f};
  const size_t rowbase = (size_t)b * LQn + q0;
  const int t0 = w * 256;
  for (int kb = t0; kb < t0 + 256; kb += 64) {
    floatx4 acc[4];
#pragma unroll
    for (int jj = 0; jj < 4; ++jj) acc[jj] = (floatx4){0.f, 0.f, 0.f, 0.f};
#pragma unroll
    for (int dc = 0; dc < 2; ++dc) {
#pragma unroll
      for (int jj = 0; jj < 4; ++jj) {
        const float* krow =
            kp + ((size_t)(b * LKn + kb + 4 * lr + jj)) * DDn + dc * 32 + lgp * 8;
        floatx4 x0 = *(const floatx4*)(krow);
        floatx4 x1 = *(const floatx4*)(krow + 4);
        half8 h;
#pragma unroll
        for (int i = 0; i < 4; ++i) { h[i] = (_Float16)x0[i]; h[i + 4] = (_Float16)x1[i]; }
        acc[jj] = __builtin_amdgcn_mfma_f32_16x16x32_f16(aq[dc], h, acc[jj], 0, 0, 0);
      }
    }
#pragma unroll
    for (int r = 0; r < 4; ++r) {
      const int row = lgp * 4 + r;
      const size_t fof = (rowbase + row) * (size_t)LKn + (size_t)(kb + 4 * lr);
      floatx4 v1 = *(const floatx4*)(f1 + fof);
      floatx4 v2 = *(const floatx4*)(f2 + fof);
      floatx4 v3 = *(const floatx4*)(f3 + fof);
      floatx4 v4 = *(const floatx4*)(f4 + fof);
      floatx4 v5 = *(const floatx4*)(f5 + fof);
      int msk[4];
      if (mode == 0) {
        intx4 m4 = *(const intx4*)((const int*)maskp + fof);
        msk[0] = (m4[0] != 0); msk[1] = (m4[1] != 0);
        msk[2] = (m4[2] != 0); msk[3] = (m4[3] != 0);
      } else if (mode == 1) {
        floatx4 m4 = *(const floatx4*)((const float*)maskp + fof);
        msk[0] = (m4[0] != 0.f); msk[1] = (m4[1] != 0.f);
        msk[2] = (m4[2] != 0.f); msk[3] = (m4[3] != 0.f);
      } else {
        unsigned mv = *(const unsigned*)((const unsigned char*)maskp + fof);
        msk[0] = (int)(mv & 0xffu); msk[1] = (int)((mv >> 8) & 0xffu);
        msk[2] = (int)((mv >> 16) & 0xffu); msk[3] = (int)((mv >> 24) & 0xffu);
      }
      floatx4 ev;
#pragma unroll
      for (int jj = 0; jj < 4; ++jj) {
        float lgt = (acc[jj][r] + v1[jj] + v2[jj] + v3[jj] + v4[jj] + v5[jj]) * 0.125f;
        float e = msk[jj] ? 0.f : __expf(lgt - 16.f);
        ev[jj] = e;
        lsum[r] += e;
      }
      *(floatx4*)(attn + fof) = ev;
    }
  }
#pragma unroll
  for (int off = 1; off < 16; off <<= 1) {
#pragma unroll
    for (int r = 0; r < 4; ++r) lsum[r] += __shfl_xor(lsum[r], off);
  }
  __shared__ float lds_l[8][16];
  if (lr == 0) {
#pragma unroll
    for (int r = 0; r < 4; ++r) lds_l[w][lgp * 4 + r] = lsum[r];
  }
  __syncthreads();
  if (tid < 16) {
    float s = 0.f;
#pragma unroll
    for (int ww = 0; ww < 8; ++ww) s += lds_l[ww][tid];
    invl[rowbase + tid] = 1.0f / s;
  }
}

__global__ __launch_bounds__(256, 4) void attn_pv_fb(
    const float* __restrict__ vp, const float* __restrict__ invl,
    float* __restrict__ attn, float* __restrict__ outp) {
  const int blk = blockIdx.x;
  const int b   = blk >> 7;
  const int q0  = (blk & 127) << 4;
  const int tid = threadIdx.x;
  const int w   = tid >> 6;
  const int l   = tid & 63;
  const int lr  = l & 15;
  const int lgp = l >> 4;
  __shared__ __align__(16) _Float16 p16[4][16][72];
  __shared__ float osum[4][16][64];
  const size_t rowbase = (size_t)b * LQn + q0;
  float il[4];
#pragma unroll
  for (int r = 0; r < 4; ++r) il[r] = invl[rowbase + lgp * 4 + r];
  floatx4 acc[4];
#pragma unroll
  for (int dt = 0; dt < 4; ++dt) acc[dt] = (floatx4){0.f, 0.f, 0.f, 0.f};
  const int t0 = w * 512;
  for (int kb = t0; kb < t0 + 512; kb += 64) {
#pragma unroll
    for (int r = 0; r < 4; ++r) {
      const int row = lgp * 4 + r;
      const size_t fof = (rowbase + row) * (size_t)LKn + (size_t)(kb + 4 * lr);
      floatx4 e = *(const floatx4*)(attn + fof);
      floatx4 p = e * il[r];
      *(floatx4*)(attn + fof) = p;
      half4 hp;
#pragma unroll
      for (int jj = 0; jj < 4; ++jj) hp[jj] = (_Float16)p[jj];
      *(half4*)(&p16[w][row][4 * lr]) = hp;
    }
    half8 pa[2];
#pragma unroll
    for (int tc = 0; tc < 2; ++tc)
      pa[tc] = *(const half8*)(&p16[w][lr][tc * 32 + lgp * 8]);
#pragma unroll
    for (int tc = 0; tc < 2; ++tc) {
#pragma unroll
      for (int dt = 0; dt < 4; ++dt) {
        const float* vbase =
            vp + ((size_t)(b * LKn + kb + tc * 32 + lgp * 8)) * DDn + dt * 16 + lr;
        half8 bv;
#pragma unroll
        for (int i = 0; i < 8; ++i) bv[i] = (_Float16)vbase[i * DDn];
        acc[dt] = __builtin_amdgcn_mfma_f32_16x16x32_f16(pa[tc], bv, acc[dt], 0, 0, 0);
      }
    }
  }
#pragma unroll
  for (int dt = 0; dt < 4; ++dt) {
#pragma unroll
    for (int r = 0; r < 4; ++r) osum[w][lgp * 4 + r][dt * 16 + lr] = acc[dt][r];
  }
  __syncthreads();
#pragma unroll
  for (int ii = 0; ii < 4; ++ii) {
    int idx = tid + 256 * ii;
    int row = idx >> 6, d = idx & 63;
    float s = osum[0][row][d] + osum[1][row][d] + osum[2][row][d] + osum[3][row][d];
    outp[(rowbase + row) * DDn + d] = s;
  }
}

extern "C" void kernel_launch(void* const* d_in, const int* in_sizes, int n_in,
                              void* d_out, int out_size, void* d_ws, size_t ws_size,
                              hipStream_t stream) {
  const float* q  = (const float*)d_in[0];
  const float* k  = (const float*)d_in[1];
  const float* v  = (const float*)d_in[2];
  const void*  mask = d_in[3];
  const float* f1 = (const float*)d_in[4];
  const float* f2 = (const float*)d_in[5];
  const float* f3 = (const float*)d_in[6];
  const float* f4 = (const float*)d_in[7];
  const float* f5 = (const float*)d_in[8];

  float* outp = (float*)d_out;
  float* attn = outp + (size_t)BBn * LQn * DDn;

  // ws layout: invl f32[16384] @0 | flag int @65536 | kh 2MB @131072 | vh 2MB
  const size_t KH_OFF = 131072, VH_OFF = KH_OFF + 2097152, NEED = VH_OFF + 2097152;
  float* invl = (float*)d_ws;
  int*   flag = (int*)((char*)d_ws + 65536);
  _Float16* kh = (_Float16*)((char*)d_ws + KH_OFF);
  _Float16* vh = (_Float16*)((char*)d_ws + VH_OFF);

  if (ws_size >= NEED) {
    prep_all<<<1025, 256, 0, stream>>>(k, v, (const unsigned*)mask, kh, vh, flag);
    attn_logits32<<<512, 512, 0, stream>>>(q, kh, f1, f2, f3, f4, f5, mask, flag, attn, invl);
    attn_pv<<<1024, 256, 0, stream>>>(vh, invl, attn, outp);
  } else {
    int* flag2 = (int*)d_ws + (BBn * LQn);
    detect_mask<<<1, 256, 0, stream>>>((const unsigned*)mask, flag2);
    attn_logits_fb<<<1024, 512, 0, stream>>>(q, k, f1, f2, f3, f4, f5, mask, flag2, attn, invl);
    attn_pv_fb<<<1024, 256, 0, stream>>>(v, invl, attn, outp);
  }
}